// Round 7
// baseline (366.412 us; speedup 1.0000x reference)
//
#include <hip/hip_runtime.h>
#include <hip/hip_fp16.h>
#include <float.h>

#define KCODES 512
#define GDIM 64
#define SBIAS 96.0f     // s = e2+96-2*x.w > 0 needs x.w < 58 (=12.7 sigma) -> safe; s < 256
#define TAUQ 0.0625f    // covers fp16 single-product err (~2x0.02) + 2 key-quant steps (2^-7); absmax 0 @R5/R6

typedef __attribute__((ext_vector_type(8))) _Float16 half8;  // 8 fp16 = 4 VGPR
typedef __attribute__((ext_vector_type(4))) float floatx4;   // MFMA C/D

// ---- workspace layout (float-index units) ----
// embT    f32[512*64]    [0, 32768)        original w, code-major
// e2      f32[512]       [32768, 33280)
// e2d     f64[512]       [33280, 34304)    (byte 133120, 8-aligned)
// emb_f16 fp16[512*64]   [34304, 50688)    fp16(-2*w), code-major

__device__ __forceinline__ void gload_lds16(const void* g, void* l) {
    __builtin_amdgcn_global_load_lds(
        (const __attribute__((address_space(1))) void*)g,
        (__attribute__((address_space(3))) void*)l, 16, 0, 0);
}

// 128 blocks x 256 = 512 waves: wave k preps code k (lane = dim g).
__launch_bounds__(256)
__global__ void prep_kernel(const float* __restrict__ w,
                            float* __restrict__ embT,
                            float* __restrict__ e2,
                            double* __restrict__ e2d,
                            short* __restrict__ emb_f16) {
    int t = blockIdx.x * 256 + threadIdx.x;   // 0..32767
    int k = t >> 6;                            // code (wave-uniform)
    int g = t & 63;                            // dim  (lane)
    float v = w[(size_t)g * KCODES + k];
    embT[(size_t)k * GDIM + g] = v;            // lane-contiguous store
    emb_f16[(size_t)k * GDIM + g] =
        (short)__half_as_ushort(__float2half(-2.0f * v));   // RNE
    float s = v * v;
    double sd = (double)v * (double)v;
#pragma unroll
    for (int off = 32; off > 0; off >>= 1) {
        s  += __shfl_xor(s, off, 64);
        sd += __shfl_xor(sd, off, 64);
    }
    if (g == 0) { e2[k] = s; e2d[k] = sd; }
}

// Fused pass A + exact fix.  GEOMETRY CHANGE (R6 post-mortem: every pipe <20%
// busy, achieved BW 570 GB/s vs R4's 950 at identical traffic -> too little
// in flight between barriers):  wave = 64 positions (4 m-tiles), block = 256
// positions, grid = 1024 blocks = exactly 4 blocks/CU, ONE resident
// generation.  Barriers per position halve; MFMA-block per barrier doubles
// (32 MFMA + 256 VALU ~ 700cy, covers the prefetch DMA latency); A-frag and
// output streams double per wave (more MLP).
// launch_bounds(256,1) ONLY — R4/R5 proved any 2nd arg > 1 squeezes the
// allocator into catastrophic spill on this kernel family.
// fp16 SINGLE-product MFMA (R5/R6-validated, absmax 0): products exact in f32
// accumulator; C preloaded with e2+96, codebook = fp16(-2w) => s = acc.
// Packed-key argmin: key = (bits(s) & ~511) | n.  Near-ties (gap <= TAUQ) ->
// LDS flag list -> in-block exact f64 rerank (lexicographic (s,k)).
__launch_bounds__(256, 1)
__global__ void vq_kernel(const float* __restrict__ x,
                          const float* __restrict__ embT,
                          const float* __restrict__ e2,
                          const double* __restrict__ e2d,
                          const short* __restrict__ emb_f16,
                          float* __restrict__ out_res,
                          float* __restrict__ out_arg) {
    __shared__ short s_cb[2][64 * 64];
    __shared__ float s_e2[512];
    __shared__ int   s_arg[256];
    __shared__ float s_fixx[4][64];
    __shared__ int   s_flags[256];
    __shared__ int   s_nflag;

    const int t = threadIdx.x;
    const int wid = t >> 6;
    const int lane = t & 63;
    const int q = lane >> 4;          // quad
    const int c = lane & 15;          // col within tile
    const int blk = blockIdx.x;
    const int grp = blk >> 8;                  // 256 blocks per group
    const int rem = blk & 255;
    const int b = rem >> 2;                    // batch  (256 pos = 1/4 slab)
    const int hwb = (rem & 3) << 8;            // block's 256-pos window in slab
    const int hw0 = hwb + wid * 64;            // wave's 64 positions

    if (t == 0) s_nflag = 0;

    // DMA geometry (chunk = 64 rows x 64 shorts = 8KB): wave wid owns LDS
    // shorts [wid*1024, +1024) = rows wid*16..wid*16+16.  Instr0 rows
    // rA=wid*16+(lane>>3), instr1 rB=rA+8 (same low-3 bits -> same granule).
    const int rA = wid * 16 + (lane >> 3);
    const int rB = rA + 8;
    const int uA = (lane & 7) ^ (lane >> 3);
    const int srcA = rA * 64 + uA * 8;   // element offset within chunk
    const int srcB = rB * 64 + uA * 8;

#define PREFETCH(CH, BUF)                                                      \
    {                                                                          \
        const short* gc_ = emb_f16 + (size_t)(CH) * 4096;                      \
        gload_lds16(gc_ + srcA, &s_cb[BUF][wid * 1024]);                       \
        gload_lds16(gc_ + srcB, &s_cb[BUF][wid * 1024 + 512]);                 \
    }

    // issue chunk-0 DMA first; e2 stage + A-frag loads below overlap it
    PREFETCH(0, 0);
    s_e2[t] = e2[t] + SBIAS;
    s_e2[t + 256] = e2[t + 256] + SBIAS;

    const float* xbase = x + (size_t)b * 262144 + (size_t)grp * 65536 + hw0;

    // A fragments: [mt][kt], fp16.  mt 0..3 -> 64 positions; 64 strided
    // dwords per lane in flight (double R6's MLP), cvt to fp16 (RNE).
    half8 a16[4][2];
#pragma unroll
    for (int mt = 0; mt < 4; ++mt)
#pragma unroll
        for (int kt = 0; kt < 2; ++kt) {
#pragma unroll
            for (int j = 0; j < 8; ++j) {
                float xv = xbase[(kt * 32 + q * 8 + j) * 1024 + mt * 16 + c];
                a16[mt][kt][j] = (_Float16)xv;
            }
        }

    unsigned best[4][4], sec[4][4];
#pragma unroll
    for (int mt = 0; mt < 4; ++mt)
#pragma unroll
        for (int r = 0; r < 4; ++r) { best[mt][r] = 0xFFFFFFFFu; sec[mt][r] = 0xFFFFFFFFu; }

    const int p8 = (q ^ (c & 7)) << 3;   // swizzled read granule (shorts)

    __syncthreads();                      // drains chunk-0 DMA + e2 stage

    int cur = 0;
    for (int ch = 0; ch < 8; ++ch) {
        if (ch < 7) PREFETCH(ch + 1, cur ^ 1);   // in flight across MFMA block
        const int C0 = ch * 64;

#pragma unroll
        for (int nt = 0; nt < 4; ++nt) {
            const int o = (nt * 16 + c) * 64 + p8;     // (r&7)==(c&7) since 16|nt*16
            half8 b0 = *(const half8*)&s_cb[cur][o];
            half8 b1 = *(const half8*)&s_cb[cur][o ^ 32];   // granule q+4 (dims 32..63)
            const float se2 = s_e2[C0 + nt * 16 + c];
            const unsigned n = (unsigned)(C0 + nt * 16 + c);
#pragma unroll
            for (int mt = 0; mt < 4; ++mt) {
                floatx4 a4 = (floatx4){se2, se2, se2, se2};   // C = e2+96 (codebook = -2w)
                a4 = __builtin_amdgcn_mfma_f32_16x16x32_f16(a16[mt][0], b0, a4, 0, 0, 0);
                a4 = __builtin_amdgcn_mfma_f32_16x16x32_f16(a16[mt][1], b1, a4, 0, 0, 0);
                // epilogue: packed key; 4 VALU/candidate (and_or, min, max, min)
#pragma unroll
                for (int r = 0; r < 4; ++r) {
                    unsigned key = (__float_as_uint(a4[r]) & ~511u) | n;
                    unsigned bo = best[mt][r];
                    best[mt][r] = bo < key ? bo : key;
                    unsigned mx = bo > key ? bo : key;
                    sec[mt][r]  = sec[mt][r] < mx ? sec[mt][r] : mx;
                }
            }
        }

        // single barrier/chunk: separates this chunk's reads of buf[cur] from
        // next iter's DMA into buf[cur], and completes DMA into buf[cur^1].
        __syncthreads();
        cur ^= 1;
    }

    // ---- cross-lane merge over the 16 cols; record args + near-tie flags
#pragma unroll
    for (int mt = 0; mt < 4; ++mt)
#pragma unroll
        for (int r = 0; r < 4; ++r) {
            unsigned b_ = best[mt][r], s_ = sec[mt][r];
#pragma unroll
            for (int sh = 1; sh < 16; sh <<= 1) {
                unsigned ob = (unsigned)__shfl_xor((int)b_, sh, 64);
                unsigned os = (unsigned)__shfl_xor((int)s_, sh, 64);
                unsigned mx = b_ > ob ? b_ : ob;           // 2nd-min of union
                s_ = s_ < os ? s_ : os;
                s_ = s_ < mx ? s_ : mx;
                b_ = b_ < ob ? b_ : ob;
            }
            if (c == 0) {
                int p = mt * 16 + q * 4 + r;           // 0..63 within wave
                s_arg[wid * 64 + p] = (int)(b_ & 511u);
                float fb = __uint_as_float(b_ & ~511u);
                float fs = __uint_as_float(s_ & ~511u);
                if (fs - fb <= TAUQ) {
                    int slot = atomicAdd(&s_nflag, 1); // cap 256 == positions/block
                    s_flags[slot] = wid * 64 + p;      // block-local position
                }
            }
        }

    // ---- result output: wave's 64 positions, lane = position.
    // Each store: 64 lanes x 4B consecutive = 256B runs.  embT gathers hit L2.
    {
        int ac = s_arg[wid * 64 + lane];
        const float* ev = embT + (size_t)ac * GDIM;
        float* rp = out_res + (size_t)b * 262144 + (size_t)grp * 65536 + hw0 + lane;
#pragma unroll 8
        for (int g = 0; g < GDIM; ++g)
            rp[(size_t)g * 1024] = ev[g] * 0.5f;
    }

    __syncthreads();
    // ---- argmin output: block's 256 positions, one coalesced pass
    out_arg[(size_t)b * 4096 + (size_t)grp * 1024 + hwb + t] = (float)s_arg[t];
    __syncthreads();   // out_arg/out_res drained before fix may overwrite

    // ---- exact f64 fix of this block's flagged positions (typ. 3-7)
    const int nf = s_nflag;
    for (int f = wid; f < nf; f += 4) {
        const int hwa = s_flags[f];                 // block-local 0..255
        const int sidx = hwb + hwa;                 // within (grp,b) slab
        // stage x-vector to LDS (lane = dim); same-wave RAW
        s_fixx[wid][lane] =
            x[(size_t)b * 262144 + (size_t)grp * 65536 + (size_t)lane * 1024 + sidx];
        asm volatile("s_waitcnt lgkmcnt(0)" ::: "memory");

        double bd = DBL_MAX; int bk = 0;
#pragma unroll 2
        for (int m = 0; m < KCODES / 64; ++m) {
            const int k = lane + m * 64;
            const float* er = embT + (size_t)k * GDIM;
            double dot = 0.0;
#pragma unroll 4
            for (int g = 0; g < GDIM; g += 4) {
                float4 e4 = *(const float4*)(er + g);
                float4 xv = *(const float4*)&s_fixx[wid][g];   // broadcast read
                dot += (double)xv.x * (double)e4.x;
                dot += (double)xv.y * (double)e4.y;
                dot += (double)xv.z * (double)e4.z;
                dot += (double)xv.w * (double)e4.w;
            }
            double s = e2d[k] - 2.0 * dot;
            if (s < bd) { bd = s; bk = k; }            // ascending k per lane
        }
        for (int off = 32; off > 0; off >>= 1) {       // lexicographic (s, k)
            double od = __shfl_down(bd, off, 64);
            int    ok = __shfl_down(bk, off, 64);
            if (od < bd || (od == bd && ok < bk)) { bd = od; bk = ok; }
        }
        bk = __shfl(bk, 0, 64);

        if (lane == 0)
            out_arg[(size_t)b * 4096 + (size_t)grp * 1024 + sidx] = (float)bk;
        out_res[(size_t)b * 262144 + (size_t)grp * 65536 + (size_t)lane * 1024 + sidx] =
            embT[(size_t)bk * GDIM + lane] * 0.5f;
    }
#undef PREFETCH
}

extern "C" void kernel_launch(void* const* d_in, const int* in_sizes, int n_in,
                              void* d_out, int out_size, void* d_ws, size_t ws_size,
                              hipStream_t stream) {
    const float* x = (const float*)d_in[0];      // (64,256,32,32) f32
    const float* w = (const float*)d_in[1];      // (64,512) f32
    float* out_res = (float*)d_out;              // 16777216 floats
    float* out_arg = (float*)d_out + 16777216;   // 262144 floats

    float*    embT    = (float*)d_ws;
    float*    e2      = embT + 32768;
    double*   e2d     = (double*)((char*)d_ws + (size_t)33280 * 4);
    short*    emb_f16 = (short*)((float*)d_ws + 34304);

    prep_kernel<<<128, 256, 0, stream>>>(w, embT, e2, e2d, emb_f16);
    vq_kernel<<<1024, 256, 0, stream>>>(x, embT, e2, e2d, emb_f16,
                                        out_res, out_arg);
}

// Round 9
// 356.647 us; speedup vs baseline: 1.0274x; 1.0274x over previous
//
#include <hip/hip_runtime.h>
#include <hip/hip_fp16.h>
#include <float.h>

#define KCODES 512
#define GDIM 64
#define SBIAS 96.0f     // s = e2+96-2*x.w > 0 needs x.w > 48+e2/2 (=12+ sigma) -> safe; s < 256
#define TAUQ 0.0625f    // fp16 single-product err + key quant; absmax 0 validated R5/R6/R7

typedef __attribute__((ext_vector_type(8))) _Float16 half8;  // 8 fp16 = 4 VGPR
typedef __attribute__((ext_vector_type(4))) float floatx4;   // MFMA C/D

// ---- workspace layout (float-index units) ----
// embT    f32[512*64]    [0, 32768)        original w, code-major
// e2      f32[512]       [32768, 33280)
// e2d     f64[512]       [33280, 34304)    (byte 133120, 8-aligned)
// emb_f16 fp16[512*64]   [34304, 50688)    fp16(-2*w), code-major

__device__ __forceinline__ void gload_lds16(const void* g, void* l) {
    __builtin_amdgcn_global_load_lds(
        (const __attribute__((address_space(1))) void*)g,
        (__attribute__((address_space(3))) void*)l, 16, 0, 0);
}

// 128 blocks x 256 = 512 waves: wave k preps code k (lane = dim g).
__launch_bounds__(256)
__global__ void prep_kernel(const float* __restrict__ w,
                            float* __restrict__ embT,
                            float* __restrict__ e2,
                            double* __restrict__ e2d,
                            short* __restrict__ emb_f16) {
    int t = blockIdx.x * 256 + threadIdx.x;   // 0..32767
    int k = t >> 6;                            // code (wave-uniform)
    int g = t & 63;                            // dim  (lane)
    float v = w[(size_t)g * KCODES + k];
    embT[(size_t)k * GDIM + g] = v;            // lane-contiguous store
    emb_f16[(size_t)k * GDIM + g] =
        (short)__half_as_ushort(__float2half(-2.0f * v));   // RNE
    float s = v * v;
    double sd = (double)v * (double)v;
#pragma unroll
    for (int off = 32; off > 0; off >>= 1) {
        s  += __shfl_xor(s, off, 64);
        sd += __shfl_xor(sd, off, 64);
    }
    if (g == 0) { e2[k] = s; e2d[k] = sd; }
}

// STRUCTURE (R8 theory, resubmitted after infra failure): all chunked /
// barriered variants pinned at ~290us regardless of geometry; R2's
// stage-once barrier-free monolith did 170us WHILE spill-crippled at 64
// VGPR.  fp16 halves the codebook to 64KB -> full-stage fits uncrippled:
// stage ONCE (8 gload_lds rounds), ONE barrier, then a barrier-free
// 32-iteration MFMA loop.  512 blocks x 512 threads (8 waves): block = 512
// positions (half slab), wave = 64 positions (4 m-tiles); 2 blocks/CU x
// ~74KB LDS (160KB cap; R2 ran 138KB); exactly one resident generation.
// launch_bounds(512, 1): declare TRUE block size, min-waves 1 only (R4/R5:
// any 2nd arg > 1 squeezes the allocator into catastrophic spill).
// fp16 single-product MFMA (R5-R7 validated, absmax 0): products exact in
// f32 acc; C preloaded with e2+96, codebook = fp16(-2w) => s = acc.
// Packed-key argmin: key = (bits(s) & ~511) | n.  Near-ties (gap <= TAUQ)
// -> LDS flag list -> in-block exact f64 rerank, 4-way ILP dot (chain 16).
__launch_bounds__(512, 1)
__global__ void vq_kernel(const float* __restrict__ x,
                          const float* __restrict__ embT,
                          const float* __restrict__ e2,
                          const double* __restrict__ e2d,
                          const short* __restrict__ emb_f16,
                          float* __restrict__ out_res,
                          float* __restrict__ out_arg) {
    __shared__ short s_cb[512 * 64];     // 64KB, swizzled full codebook
    __shared__ float s_e2[512];
    __shared__ int   s_arg[512];
    __shared__ float s_fixx[8][64];
    __shared__ int   s_flags[512];
    __shared__ int   s_nflag;

    const int t = threadIdx.x;           // 0..511
    const int wid = t >> 6;              // 0..7
    const int lane = t & 63;
    const int q = lane >> 4;             // quad
    const int c = lane & 15;             // col within tile
    const int blk = blockIdx.x;          // 0..511
    const int grp = blk >> 7;            // 4 groups x 128 blocks
    const int rem = blk & 127;
    const int b = rem >> 1;              // batch
    const int half = rem & 1;
    const int hw0 = half * 512 + wid * 64;   // wave's 64 positions in slab

    if (t == 0) s_nflag = 0;

    // ---- stage full codebook, swizzled: LDS(row R, granule u) holds
    // emb(R, u ^ (R&7)).  gload_lds dest = wave-uniform base + lane*16B
    // (linear); swizzle applied on the per-lane GLOBAL source address.
    // Round i: wave wid covers rows i*64 + wid*8 .. +8.
    {
        const int rlo = wid * 8 + (lane >> 3);               // row mod 64
        const int u = ((lane & 7) ^ (lane >> 3)) << 3;       // swizzled granule
#pragma unroll
        for (int i = 0; i < 8; ++i) {
            const int r = i * 64 + rlo;
            gload_lds16(emb_f16 + r * 64 + u, &s_cb[i * 4096 + wid * 512]);
        }
    }
    s_e2[t & 511] = e2[t & 511] + SBIAS;

    // ---- A fragments (overlap the DMA): [mt][kt], fp16, 64 strided dwords.
    const float* xbase = x + (size_t)b * 262144 + (size_t)grp * 65536 + hw0;
    half8 a16[4][2];
#pragma unroll
    for (int mt = 0; mt < 4; ++mt)
#pragma unroll
        for (int kt = 0; kt < 2; ++kt) {
#pragma unroll
            for (int j = 0; j < 8; ++j) {
                float xv = xbase[(kt * 32 + q * 8 + j) * 1024 + mt * 16 + c];
                a16[mt][kt][j] = (_Float16)xv;
            }
        }

    unsigned best[4][4], sec[4][4];
#pragma unroll
    for (int mt = 0; mt < 4; ++mt)
#pragma unroll
        for (int r = 0; r < 4; ++r) { best[mt][r] = 0xFFFFFFFFu; sec[mt][r] = 0xFFFFFFFFu; }

    const int p8 = (q ^ (c & 7)) << 3;   // swizzled read granule (shorts)

    __syncthreads();   // the ONLY pre-output barrier: drains DMA (vmcnt) + e2

    // ---- barrier-free main loop: 32 row-tiles x (2 ds_read + 8 MFMA + key)
#pragma unroll 4
    for (int nt = 0; nt < 32; ++nt) {
        const int o = (nt * 16 + c) * 64 + p8;     // row nt*16+c; (r&7)==(c&7)
        half8 b0 = *(const half8*)&s_cb[o];        // kt=0 dims (granule q)
        half8 b1 = *(const half8*)&s_cb[o ^ 32];   // granule q+4 -> dims 32..63
        const float se2 = s_e2[nt * 16 + c];
        const unsigned n = (unsigned)(nt * 16 + c);
#pragma unroll
        for (int mt = 0; mt < 4; ++mt) {
            floatx4 a4 = (floatx4){se2, se2, se2, se2};   // C = e2+96 (codebook = -2w)
            a4 = __builtin_amdgcn_mfma_f32_16x16x32_f16(a16[mt][0], b0, a4, 0, 0, 0);
            a4 = __builtin_amdgcn_mfma_f32_16x16x32_f16(a16[mt][1], b1, a4, 0, 0, 0);
#pragma unroll
            for (int r = 0; r < 4; ++r) {
                unsigned key = (__float_as_uint(a4[r]) & ~511u) | n;
                unsigned bo = best[mt][r];
                best[mt][r] = bo < key ? bo : key;
                unsigned mx = bo > key ? bo : key;
                sec[mt][r]  = sec[mt][r] < mx ? sec[mt][r] : mx;
            }
        }
    }

    // ---- cross-lane merge over the 16 cols; record args + near-tie flags
#pragma unroll
    for (int mt = 0; mt < 4; ++mt)
#pragma unroll
        for (int r = 0; r < 4; ++r) {
            unsigned b_ = best[mt][r], s_ = sec[mt][r];
#pragma unroll
            for (int sh = 1; sh < 16; sh <<= 1) {
                unsigned ob = (unsigned)__shfl_xor((int)b_, sh, 64);
                unsigned os = (unsigned)__shfl_xor((int)s_, sh, 64);
                unsigned mx = b_ > ob ? b_ : ob;           // 2nd-min of union
                s_ = s_ < os ? s_ : os;
                s_ = s_ < mx ? s_ : mx;
                b_ = b_ < ob ? b_ : ob;
            }
            if (c == 0) {
                int p = mt * 16 + q * 4 + r;           // 0..63 within wave
                s_arg[wid * 64 + p] = (int)(b_ & 511u);
                float fb = __uint_as_float(b_ & ~511u);
                float fs = __uint_as_float(s_ & ~511u);
                if (fs - fb <= TAUQ) {
                    int slot = atomicAdd(&s_nflag, 1); // cap 512 == positions/block
                    s_flags[slot] = wid * 64 + p;      // block-local position
                }
            }
        }

    // ---- result output: wave's 64 positions, lane = position (256B runs)
    {
        int ac = s_arg[wid * 64 + lane];
        const float* ev = embT + (size_t)ac * GDIM;
        float* rp = out_res + (size_t)b * 262144 + (size_t)grp * 65536 + hw0 + lane;
#pragma unroll 8
        for (int g = 0; g < GDIM; ++g)
            rp[(size_t)g * 1024] = ev[g] * 0.5f;
    }

    __syncthreads();
    // ---- argmin output: block's 512 positions, one coalesced pass
    out_arg[(size_t)b * 4096 + (size_t)grp * 1024 + half * 512 + t] =
        (float)s_arg[t];
    __syncthreads();   // out_arg/out_res drained before fix may overwrite

    // ---- exact f64 fix of flagged positions; 8 waves stride the list.
    // 4 parallel f64 accumulators: dependent chain 64 -> 16.
    const int nf = s_nflag;
    for (int f = wid; f < nf; f += 8) {
        const int hwa = s_flags[f];                 // block-local 0..511
        const int sidx = half * 512 + hwa;          // within (grp,b) slab
        // stage x-vector to LDS (lane = dim); same-wave RAW
        s_fixx[wid][lane] =
            x[(size_t)b * 262144 + (size_t)grp * 65536 + (size_t)lane * 1024 + sidx];
        asm volatile("s_waitcnt lgkmcnt(0)" ::: "memory");

        double bd = DBL_MAX; int bk = 0;
        for (int m = 0; m < KCODES / 64; ++m) {
            const int k = lane + m * 64;
            const float* er = embT + (size_t)k * GDIM;
            double d0 = 0.0, d1 = 0.0, d2 = 0.0, d3 = 0.0;
#pragma unroll
            for (int gg = 0; gg < 4; ++gg) {
#pragma unroll
                for (int u4 = 0; u4 < 4; ++u4) {
                    const int g = (gg * 4 + u4) * 4;
                    float4 e4 = *(const float4*)(er + g);
                    float4 xv = *(const float4*)&s_fixx[wid][g];   // broadcast
                    double p = (double)xv.x * (double)e4.x
                             + (double)xv.y * (double)e4.y;
                    double pq = (double)xv.z * (double)e4.z
                              + (double)xv.w * (double)e4.w;
                    if (u4 == 0) d0 += p + pq;
                    else if (u4 == 1) d1 += p + pq;
                    else if (u4 == 2) d2 += p + pq;
                    else d3 += p + pq;
                }
            }
            double s = e2d[k] - 2.0 * ((d0 + d1) + (d2 + d3));
            if (s < bd) { bd = s; bk = k; }            // ascending k per lane
        }
        for (int off = 32; off > 0; off >>= 1) {       // lexicographic (s, k)
            double od = __shfl_down(bd, off, 64);
            int    ok = __shfl_down(bk, off, 64);
            if (od < bd || (od == bd && ok < bk)) { bd = od; bk = ok; }
        }
        bk = __shfl(bk, 0, 64);

        if (lane == 0)
            out_arg[(size_t)b * 4096 + (size_t)grp * 1024 + sidx] = (float)bk;
        out_res[(size_t)b * 262144 + (size_t)grp * 65536 + (size_t)lane * 1024 + sidx] =
            embT[(size_t)bk * GDIM + lane] * 0.5f;
    }
}

extern "C" void kernel_launch(void* const* d_in, const int* in_sizes, int n_in,
                              void* d_out, int out_size, void* d_ws, size_t ws_size,
                              hipStream_t stream) {
    const float* x = (const float*)d_in[0];      // (64,256,32,32) f32
    const float* w = (const float*)d_in[1];      // (64,512) f32
    float* out_res = (float*)d_out;              // 16777216 floats
    float* out_arg = (float*)d_out + 16777216;   // 262144 floats

    float*    embT    = (float*)d_ws;
    float*    e2      = embT + 32768;
    double*   e2d     = (double*)((char*)d_ws + (size_t)33280 * 4);
    short*    emb_f16 = (short*)((float*)d_ws + 34304);

    prep_kernel<<<128, 256, 0, stream>>>(w, embT, e2, e2d, emb_f16);
    vq_kernel<<<512, 512, 0, stream>>>(x, embT, e2, e2d, emb_f16,
                                       out_res, out_arg);
}

// Round 10
// 228.100 us; speedup vs baseline: 1.6064x; 1.5636x over previous
//
#include <hip/hip_runtime.h>
#include <float.h>

#define KCODES 512
#define GDIM 64
#define TAU 4.0e-3f   // split-bf16 3-product err ~3e-4 << TAU; ~800 flags total, exact f64 fix
                      // (validated absmax 0 in R3 with this exact numeric path)

typedef __attribute__((ext_vector_type(8))) short short8;   // 8 bf16 = 4 VGPR
typedef __attribute__((ext_vector_type(4))) float floatx4;  // MFMA C/D

__device__ __forceinline__ void bf16split(float x, short& hi, short& lo) {
    unsigned u = __float_as_uint(x);
    unsigned h = (u + 0x7fffu + ((u >> 16) & 1u)) >> 16;   // RNE to bf16
    hi = (short)h;
    float hf = __uint_as_float(h << 16);
    float l = x - hf;                                      // exact in f32
    unsigned ul = __float_as_uint(l);
    lo = (short)((ul + 0x7fffu + ((ul >> 16) & 1u)) >> 16);
}

// SINGLE-DISPATCH fused kernel (R10): every 2-dispatch round showed a fixed
// ~60-76us of (total - sum(kernels)); prep's work is tiny, so fold it into
// vq and launch ONCE.  Each block self-stages the codebook from w:
//   per chunk: issue 16 coalesced f32 loads of the NEXT chunk (T14 split:
//   issue early, convert+ds_write late, hidden under the MFMA block),
//   bf16split(-2v) -> swizzled ds_write_b128 (write-side XOR == read-side p8
//   mapping), per-code e2 via LDS atomicAdd (4 partials/code; zero-init
//   race-fenced by a dedicated pre-loop barrier).
// embT / e2 / e2d workspace ELIMINATED: result output + f64 fix read w
// columns directly (coalesced across lanes); e2d folded into the fix as
// s = sum e*(e-2x) in f64 (identical ranking to e2d-2dot).
// Numerics = R3's validated path: 3-product split-bf16 MFMA (C preloaded
// with e2, codebook=-2w), fmed3 float second-min, TAU=4e-3, lexicographic
// (s,k) exact rerank.  Chassis = R3: 2048x256, (256,1) [R4/R5: any 2nd arg
// >1 is catastrophic], chunk=64 double-buffer, ~36KB LDS -> 4 blocks/CU.
__launch_bounds__(256, 1)
__global__ void vq_kernel(const float* __restrict__ x,
                          const float* __restrict__ w,
                          float* __restrict__ out_res,
                          float* __restrict__ out_arg) {
    __shared__ short s_hi[2][64 * 64];
    __shared__ short s_lo[2][64 * 64];
    __shared__ float s_e2[512];
    __shared__ int   s_arg[128];
    __shared__ float s_fixx[4][64];
    __shared__ int   s_flags[128];
    __shared__ int   s_nflag;

    const int t = threadIdx.x;
    const int wid = t >> 6;
    const int lane = t & 63;
    const int q = lane >> 4;          // quad
    const int c = lane & 15;          // col within tile
    const int blk = blockIdx.x;
    const int grp = blk >> 9;                          // 512 blocks per group
    const int posbase = ((blk & 511) << 7) + wid * 32; // wave's 32 positions
    const int b = posbase >> 10;
    const int hwb = posbase & 1023;

    if (t == 0) s_nflag = 0;
    s_e2[t] = 0.0f;
    s_e2[t + 256] = 0.0f;

    // ---- staging identity: thread t <-> (code j within chunk, dim-quad qq).
    // Thread loads dims qq*16..qq*16+15 of code C0+j = granules 2qq, 2qq+1.
    // Write-side swizzle: LDS(row j, granule u^(j&7)) <- emb granule u; the
    // read side (p8 below) applies the same XOR -> consistent; both sides at
    // the 1KB/8clk b128 bank floor.
    const int j  = t & 63;
    const int qq = t >> 6;
    const int u0 = (((2 * qq)     ^ (j & 7)) << 3);   // short offsets in row
    const int u1 = (((2 * qq + 1) ^ (j & 7)) << 3);
    const float* wbase = w + (size_t)(qq * 16) * KCODES + j;   // +i*512 +C0

#define STAGE_WRITE(BUF, C0)                                                   \
    {                                                                          \
        short8 hA, hB, lA, lB;                                                 \
        float e2p = 0.0f;                                                      \
        _Pragma("unroll")                                                      \
        for (int i = 0; i < 8; ++i) {                                          \
            short h_, l_;                                                      \
            bf16split(-2.0f * wv[i], h_, l_);                                  \
            hA[i] = h_; lA[i] = l_;                                            \
            e2p = __fmaf_rn(wv[i], wv[i], e2p);                                \
        }                                                                      \
        _Pragma("unroll")                                                      \
        for (int i = 0; i < 8; ++i) {                                          \
            short h_, l_;                                                      \
            bf16split(-2.0f * wv[8 + i], h_, l_);                              \
            hB[i] = h_; lB[i] = l_;                                            \
            e2p = __fmaf_rn(wv[8 + i], wv[8 + i], e2p);                        \
        }                                                                      \
        *(short8*)&s_hi[BUF][j * 64 + u0] = hA;                                \
        *(short8*)&s_hi[BUF][j * 64 + u1] = hB;                                \
        *(short8*)&s_lo[BUF][j * 64 + u0] = lA;                                \
        *(short8*)&s_lo[BUF][j * 64 + u1] = lB;                                \
        atomicAdd(&s_e2[(C0) + j], e2p);                                       \
    }

    // ---- chunk-0 loads issue first; A-frag x loads overlap them
    float wv[16];
#pragma unroll
    for (int i = 0; i < 16; ++i) wv[i] = wbase[i * KCODES];

    const float* xbase = x + (size_t)b * 262144 + (size_t)grp * 65536 + hwb;

    // A fragments: [mt][kt], hi and lo. 8 strided dwords each, split to bf16.
    short8 ahi[2][2], alo[2][2];
#pragma unroll
    for (int mt = 0; mt < 2; ++mt)
#pragma unroll
        for (int kt = 0; kt < 2; ++kt) {
#pragma unroll
            for (int jj = 0; jj < 8; ++jj) {
                float xv = xbase[(kt * 32 + q * 8 + jj) * 1024 + mt * 16 + c];
                short h, l; bf16split(xv, h, l);
                ahi[mt][kt][jj] = h; alo[mt][kt][jj] = l;
            }
        }

    float best[2][4], sec[2][4]; int arg[2][4];
#pragma unroll
    for (int mt = 0; mt < 2; ++mt)
#pragma unroll
        for (int r = 0; r < 4; ++r) { best[mt][r] = FLT_MAX; sec[mt][r] = FLT_MAX; arg[mt][r] = 0; }

    const int p8 = (q ^ (c & 7)) << 3;   // swizzled read granule (shorts)

    __syncthreads();                 // e2 zero-init visible before any atomicAdd
    STAGE_WRITE(0, 0);               // chunk 0 -> buf 0 (+ e2 adds for codes 0..63)
    __syncthreads();                 // buf0 + e2(chunk0) resident

    int cur = 0;
    for (int ch = 0; ch < 8; ++ch) {
        // T14 split: issue NEXT chunk's w loads now; convert/write after MFMA.
        if (ch < 7) {
#pragma unroll
            for (int i = 0; i < 16; ++i) wv[i] = wbase[i * KCODES + (ch + 1) * 64];
        }
        const int C0 = ch * 64;

#pragma unroll
        for (int nt = 0; nt < 4; ++nt) {
            const int o = (nt * 16 + c) * 64 + p8;     // (r&7)==(c&7) since 16|nt*16
            short8 bh0 = *(const short8*)&s_hi[cur][o];
            short8 bh1 = *(const short8*)&s_hi[cur][o ^ 32];   // granule q+4
            short8 bl0 = *(const short8*)&s_lo[cur][o];
            short8 bl1 = *(const short8*)&s_lo[cur][o ^ 32];
            const float se2 = s_e2[C0 + nt * 16 + c];
            const int   n   = C0 + nt * 16 + c;
#pragma unroll
            for (int mt = 0; mt < 2; ++mt) {
                floatx4 a4 = (floatx4){se2, se2, se2, se2};   // C = e2 (codebook = -2w)
                a4 = __builtin_amdgcn_mfma_f32_16x16x32_bf16(alo[mt][0], bh0, a4, 0, 0, 0);
                a4 = __builtin_amdgcn_mfma_f32_16x16x32_bf16(ahi[mt][0], bl0, a4, 0, 0, 0);
                a4 = __builtin_amdgcn_mfma_f32_16x16x32_bf16(ahi[mt][0], bh0, a4, 0, 0, 0);
                a4 = __builtin_amdgcn_mfma_f32_16x16x32_bf16(alo[mt][1], bh1, a4, 0, 0, 0);
                a4 = __builtin_amdgcn_mfma_f32_16x16x32_bf16(ahi[mt][1], bl1, a4, 0, 0, 0);
                a4 = __builtin_amdgcn_mfma_f32_16x16x32_bf16(ahi[mt][1], bh1, a4, 0, 0, 0);
#pragma unroll
                for (int r = 0; r < 4; ++r) {
                    float s = a4[r];
                    float bo = best[mt][r];
                    best[mt][r] = fminf(bo, s);
                    arg[mt][r]  = (s < bo) ? n : arg[mt][r];
                    sec[mt][r]  = __builtin_amdgcn_fmed3f(bo, sec[mt][r], s);
                }
            }
        }

        // convert + swizzled write of chunk ch+1 into buf^1 (loads drained here)
        if (ch < 7) STAGE_WRITE(cur ^ 1, C0 + 64);

        // single barrier/chunk: this chunk's reads of buf[cur] done; next
        // chunk's writes into buf[cur^1] + its e2 adds complete.
        __syncthreads();
        cur ^= 1;
    }

    // ---- cross-lane merge over the 16 cols; record args + near-tie flags
#pragma unroll
    for (int mt = 0; mt < 2; ++mt)
#pragma unroll
        for (int r = 0; r < 4; ++r) {
            float b_ = best[mt][r], s_ = sec[mt][r]; int n_ = arg[mt][r];
#pragma unroll
            for (int sh = 1; sh < 16; sh <<= 1) {
                float ob = __shfl_xor(b_, sh, 64);
                float os = __shfl_xor(s_, sh, 64);
                int   on = __shfl_xor(n_, sh, 64);
                float bo = b_;
                b_ = fminf(bo, ob);
                n_ = (ob < bo) ? on : n_;
                s_ = fminf(fminf(s_, os), fmaxf(bo, ob));   // 2nd-min of union
            }
            if (c == 0) {
                int p = mt * 16 + q * 4 + r;           // 0..31 within wave
                s_arg[wid * 32 + p] = n_;
                if (s_ - b_ <= TAU) {
                    int slot = atomicAdd(&s_nflag, 1); // cap 128 == positions/block
                    s_flags[slot] = wid * 32 + p;      // block-local position
                }
            }
        }

    // ---- result output: wave's 32 positions, from w columns (L2-hot 128KB)
    {
        int p = lane & 31, gi = lane >> 5;
        int ac = s_arg[wid * 32 + p];
        float* rp = out_res + (size_t)b * 262144 + (size_t)grp * 65536 + hwb + p;
#pragma unroll
        for (int it = 0; it < 32; ++it) {
            int g = it * 2 + gi;
            rp[(size_t)g * 1024] = w[(size_t)g * KCODES + ac] * 0.5f;
        }
    }

    __syncthreads();
    // ---- argmin output: block's 128 positions, one coalesced pass
    if (t < 128) {
        int bp = ((blk & 511) << 7) + t;
        out_arg[(size_t)(bp >> 10) * 4096 + (size_t)grp * 1024 + (bp & 1023)] =
            (float)s_arg[t];
    }
    __syncthreads();   // out_arg/out_res drained before fix may overwrite

    // ---- exact f64 fix of this block's flagged positions (typ. 0-1).
    // s = sum_g e*(e - 2x) in f64  ==  e2d - 2*dot (identical ranking);
    // w-column loads are coalesced across lanes (k = lane + m*64).
    const int nf = s_nflag;
    for (int f = wid; f < nf; f += 4) {
        const int hwa = s_flags[f];                 // block-local 0..127
        const int pos = ((blk & 511) << 7) + hwa;   // position within (grp) slab
        const int fb = pos >> 10;
        const int sidx = pos & 1023;
        // stage x-vector to LDS (lane = dim); same-wave RAW
        s_fixx[wid][lane] =
            x[(size_t)fb * 262144 + (size_t)grp * 65536 + (size_t)lane * 1024 + sidx];
        asm volatile("s_waitcnt lgkmcnt(0)" ::: "memory");

        double bd = DBL_MAX; int bk = 0;
        for (int m = 0; m < KCODES / 64; ++m) {
            const int k = lane + m * 64;
            double d0 = 0.0, d1 = 0.0, d2 = 0.0, d3 = 0.0;
#pragma unroll
            for (int g = 0; g < GDIM; g += 4) {
                double e0 = (double)w[(size_t)(g + 0) * KCODES + k];
                double e1 = (double)w[(size_t)(g + 1) * KCODES + k];
                double e2v = (double)w[(size_t)(g + 2) * KCODES + k];
                double e3 = (double)w[(size_t)(g + 3) * KCODES + k];
                d0 += e0 * (e0 - 2.0 * (double)s_fixx[wid][g + 0]);
                d1 += e1 * (e1 - 2.0 * (double)s_fixx[wid][g + 1]);
                d2 += e2v * (e2v - 2.0 * (double)s_fixx[wid][g + 2]);
                d3 += e3 * (e3 - 2.0 * (double)s_fixx[wid][g + 3]);
            }
            double s = (d0 + d1) + (d2 + d3);
            if (s < bd) { bd = s; bk = k; }            // ascending k per lane
        }
        for (int off = 32; off > 0; off >>= 1) {       // lexicographic (s, k)
            double od = __shfl_down(bd, off, 64);
            int    ok = __shfl_down(bk, off, 64);
            if (od < bd || (od == bd && ok < bk)) { bd = od; bk = ok; }
        }
        bk = __shfl(bk, 0, 64);

        if (lane == 0)
            out_arg[(size_t)fb * 4096 + (size_t)grp * 1024 + sidx] = (float)bk;
        out_res[(size_t)fb * 262144 + (size_t)grp * 65536 + (size_t)lane * 1024 + sidx] =
            w[(size_t)lane * KCODES + bk] * 0.5f;
    }
#undef STAGE_WRITE
}

extern "C" void kernel_launch(void* const* d_in, const int* in_sizes, int n_in,
                              void* d_out, int out_size, void* d_ws, size_t ws_size,
                              hipStream_t stream) {
    const float* x = (const float*)d_in[0];      // (64,256,32,32) f32
    const float* w = (const float*)d_in[1];      // (64,512) f32
    float* out_res = (float*)d_out;              // 16777216 floats
    float* out_arg = (float*)d_out + 16777216;   // 262144 floats
    (void)d_ws; (void)ws_size;                   // no workspace needed

    vq_kernel<<<2048, 256, 0, stream>>>(x, w, out_res, out_arg);
}